// Round 1
// 1131.726 us; speedup vs baseline: 1.1224x; 1.1224x over previous
//
#include <hip/hip_runtime.h>

#define L 1024
#define DD 1024
#define BATCH 32
#define M_TOTAL (BATCH * L)  // 32768

typedef _Float16 f16;
typedef __attribute__((ext_vector_type(4))) _Float16 f16x4;
typedef __attribute__((ext_vector_type(8))) _Float16 f16x8;
typedef __attribute__((ext_vector_type(4))) float f32x4;

// async global->LDS, 16B per lane. LDS dest = wave-uniform base + lane*16.
__device__ __forceinline__ void load16_lds(const void* g, void* l) {
  __builtin_amdgcn_global_load_lds(
      (const __attribute__((address_space(1))) unsigned int*)g,
      (__attribute__((address_space(3))) unsigned int*)l,
      16, 0, 0);
}

// ---------------- small prep kernels ----------------

__global__ void gather_x_kernel(const int* __restrict__ positives,
                                const float* __restrict__ item_emb,
                                const float* __restrict__ pos_emb,
                                f16* __restrict__ x) {
  const int bl = blockIdx.x;
  const int lpos = bl & (L - 1);
  const int idx = positives[bl];
  const int d = threadIdx.x * 4;
  const float4 ie = *(const float4*)(item_emb + (size_t)idx * DD + d);
  const float4 pe = *(const float4*)(pos_emb + (size_t)lpos * DD + d);
  f16x4 h;
  h[0] = (f16)(ie.x + pe.x);
  h[1] = (f16)(ie.y + pe.y);
  h[2] = (f16)(ie.z + pe.z);
  h[3] = (f16)(ie.w + pe.w);
  *(f16x4*)(x + (size_t)bl * DD + d) = h;
}

__global__ void cast_w_kernel(const float* __restrict__ src, f16* __restrict__ dst) {
  const int i = (blockIdx.x * 256 + threadIdx.x) * 4;
  const float4 v = *(const float4*)(src + i);
  f16x4 h;
  h[0] = (f16)v.x; h[1] = (f16)v.y; h[2] = (f16)v.z; h[3] = (f16)v.w;
  *(f16x4*)(dst + i) = h;
}

// per-batch 1024x1024 f16 transpose via 64x64 LDS tiles
__global__ void transpose_v_kernel(const unsigned short* __restrict__ vin,
                                   unsigned short* __restrict__ vout) {
  const int b = blockIdx.z;
  const unsigned short* in = vin + (size_t)b * L * DD;
  unsigned short* out = vout + (size_t)b * L * DD;
  const int r0 = blockIdx.x * 64, c0 = blockIdx.y * 64;
  __shared__ unsigned short t[64][65];
  const int tid = threadIdx.x;
  for (int c = tid; c < 1024; c += 256) {
    const int r = c >> 4, cc = (c & 15) * 4;
    const ushort4 vv = *(const ushort4*)(in + (size_t)(r0 + r) * DD + c0 + cc);
    t[r][cc] = vv.x; t[r][cc + 1] = vv.y; t[r][cc + 2] = vv.z; t[r][cc + 3] = vv.w;
  }
  __syncthreads();
  for (int c = tid; c < 1024; c += 256) {
    const int r = c >> 4, cc = (c & 15) * 4;
    ushort4 vv;
    vv.x = t[cc][r]; vv.y = t[cc + 1][r]; vv.z = t[cc + 2][r]; vv.w = t[cc + 3][r];
    *(ushort4*)(out + (size_t)(c0 + r) * L + r0 + cc) = vv;
  }
}

// ---------------- 256x256 8-phase dense GEMM: C = A(MxK,ldA) * B^T (NxK,ld 1024) -----
// BK=64, 8 waves (2M x 4N), 512 threads, 128KB dynamic LDS double-buffer.
// T3+T4: counted vmcnt(8) at tile boundaries (never 0 in steady state); stages for
// tile t+2 issue in phases 2-3 of tile t (after that buffer's reads completed).
// T5: setprio around MFMA clusters. T1: bijective XCD swizzle (grid % 8 == 0).
// LDS layout per buf/mat: [chunk c=k/8][row][8 f16] -> conflict-free ds_read_b128
// (same pattern as the previous kernel: measured SQ_LDS_BANK_CONFLICT = 0).
// EPI 0: silu. EPI 1: (acc*gamma+beta)*scale with gn>=1024 -> (g1,b1).

#define LDSOFF(d, mt, c, r) (((((d) * 2 + (mt)) * 8 + (c)) * 256 + (r)) * 8)

template <int EPI, int NTN>  // NTN = N/256 (power of 2)
__global__ __launch_bounds__(512, 2) void gemm256_kernel(
    const f16* __restrict__ A, const f16* __restrict__ B, f16* __restrict__ Cout,
    const size_t ldA, const size_t ldC,
    const float* __restrict__ g0, const float* __restrict__ b0,
    const float* __restrict__ g1, const float* __restrict__ b1, const float scale) {
  extern __shared__ f16 lds[];  // [2 buf][2 mat][8 chunk][256 row][8] = 128KB
  const int bid = blockIdx.x;
  const int cpx = gridDim.x >> 3;                    // blocks per XCD (grid % 8 == 0)
  const int logical = (bid & 7) * cpx + (bid >> 3);  // contiguous range per XCD
  const int mt = logical / NTN, nt = logical % NTN;
  const int tm0 = mt * 256, tn0 = nt * 256;
  const int tid = threadIdx.x;
  const int w = tid >> 6, l = tid & 63;
  const int wr = w >> 2, wc = w & 3;           // wave tile: rows wr*128+, cols wc*64+
  const int qd = l >> 4, mlo = l & 15;
  const int c1 = w >> 1, rbh = w & 1;          // staging task split
  const f16* Ag = A + (size_t)tm0 * ldA;
  const f16* Bg = B + (size_t)tn0 * 1024;

  // one sigma-op: half-tile h (0=rows 0-127, 1=rows 128-255), 2 loads/thread
  auto stageA = [&](int dd, int h, int k0) {
    const int rb = h * 2 + rbh;
    load16_lds(Ag + (size_t)(rb * 64 + l) * ldA + k0 + c1 * 8,
               lds + LDSOFF(dd, 0, c1, rb * 64));
    load16_lds(Ag + (size_t)(rb * 64 + l) * ldA + k0 + (c1 + 4) * 8,
               lds + LDSOFF(dd, 0, c1 + 4, rb * 64));
  };
  auto stageB = [&](int dd, int h, int k0) {
    const int rb = h * 2 + rbh;
    load16_lds(Bg + (size_t)(rb * 64 + l) * 1024 + k0 + c1 * 8,
               lds + LDSOFF(dd, 1, c1, rb * 64));
    load16_lds(Bg + (size_t)(rb * 64 + l) * 1024 + k0 + (c1 + 4) * 8,
               lds + LDSOFF(dd, 1, c1 + 4, rb * 64));
  };

  f32x4 acc[8][4] = {};

  // prologue: tile 0 fully (8 loads, oldest), then tile 1 fully (8 loads)
  stageA(0, 0, 0); stageA(0, 1, 0); stageB(0, 0, 0); stageB(0, 1, 0);
  asm volatile("" ::: "memory");  // keep t0 loads older than t1 loads
  stageA(1, 0, 64); stageA(1, 1, 64); stageB(1, 0, 64); stageB(1, 1, 64);
  asm volatile("s_waitcnt vmcnt(8)" ::: "memory");  // t0 landed; t1 (8) in flight
  __builtin_amdgcn_s_barrier();

#define LDA(mi, s) (*(const f16x8*)(lds + LDSOFF(d, 0, (s) * 4 + qd, wr * 128 + (mi) * 16 + mlo)))
#define LDB(ni, s) (*(const f16x8*)(lds + LDSOFF(d, 1, (s) * 4 + qd, wc * 64 + (ni) * 16 + mlo)))
#define MFMA16(a, b, c) __builtin_amdgcn_mfma_f32_16x16x32_f16(a, b, c, 0, 0, 0)

#pragma unroll 2
  for (int t = 0; t < 16; ++t) {
    const int d = t & 1;
    const int k2 = (t + 2) * 64;
    f16x8 a0[4][2], a1[4][2], bA[2][2], bB[2][2];
    // ---- phase 0: read A m0-3, B n0-1; MFMA Q(0,0)
#pragma unroll
    for (int m = 0; m < 4; ++m) { a0[m][0] = LDA(m, 0); a0[m][1] = LDA(m, 1); }
#pragma unroll
    for (int n = 0; n < 2; ++n) { bA[n][0] = LDB(n, 0); bA[n][1] = LDB(n, 1); }
    __builtin_amdgcn_s_barrier();
    __builtin_amdgcn_s_setprio(1);
#pragma unroll
    for (int m = 0; m < 4; ++m)
#pragma unroll
      for (int n = 0; n < 2; ++n) {
        acc[m][n] = MFMA16(a0[m][0], bA[n][0], acc[m][n]);
        acc[m][n] = MFMA16(a0[m][1], bA[n][1], acc[m][n]);
      }
    __builtin_amdgcn_s_setprio(0);
    __builtin_amdgcn_s_barrier();
    // ---- phase 1: read B n2-3; MFMA Q(0,1)
#pragma unroll
    for (int n = 0; n < 2; ++n) { bB[n][0] = LDB(n + 2, 0); bB[n][1] = LDB(n + 2, 1); }
    __builtin_amdgcn_s_barrier();
    __builtin_amdgcn_s_setprio(1);
#pragma unroll
    for (int m = 0; m < 4; ++m)
#pragma unroll
      for (int n = 0; n < 2; ++n) {
        acc[m][n + 2] = MFMA16(a0[m][0], bB[n][0], acc[m][n + 2]);
        acc[m][n + 2] = MFMA16(a0[m][1], bB[n][1], acc[m][n + 2]);
      }
    __builtin_amdgcn_s_setprio(0);
    __builtin_amdgcn_s_barrier();
    // ---- phase 2: read A m4-7; stage B(t+2) into buf d (B(t) fully read at P1);
    //      MFMA Q(1,0)
#pragma unroll
    for (int m = 0; m < 4; ++m) { a1[m][0] = LDA(m + 4, 0); a1[m][1] = LDA(m + 4, 1); }
    if (t < 14) { stageB(d, 0, k2); stageB(d, 1, k2); }
    __builtin_amdgcn_s_barrier();
    __builtin_amdgcn_s_setprio(1);
#pragma unroll
    for (int m = 0; m < 4; ++m)
#pragma unroll
      for (int n = 0; n < 2; ++n) {
        acc[m + 4][n] = MFMA16(a1[m][0], bA[n][0], acc[m + 4][n]);
        acc[m + 4][n] = MFMA16(a1[m][1], bA[n][1], acc[m + 4][n]);
      }
    __builtin_amdgcn_s_setprio(0);
    __builtin_amdgcn_s_barrier();
    // ---- phase 3: stage A(t+2) into buf d (A(t) fully read at P2); MFMA Q(1,1);
    //      boundary: counted vmcnt(8) leaves exactly tile t+2's 8 loads in flight,
    //      guaranteeing tile t+1 (staged during t-1) fully landed. Drain only at t=14.
    if (t < 14) { stageA(d, 0, k2); stageA(d, 1, k2); }
    __builtin_amdgcn_s_barrier();
    __builtin_amdgcn_s_setprio(1);
#pragma unroll
    for (int m = 0; m < 4; ++m)
#pragma unroll
      for (int n = 0; n < 2; ++n) {
        acc[m + 4][n + 2] = MFMA16(a1[m][0], bB[n][0], acc[m + 4][n + 2]);
        acc[m + 4][n + 2] = MFMA16(a1[m][1], bB[n][1], acc[m + 4][n + 2]);
      }
    __builtin_amdgcn_s_setprio(0);
    if (t < 14) {
      asm volatile("s_waitcnt vmcnt(8)" ::: "memory");
    } else if (t == 14) {
      asm volatile("s_waitcnt vmcnt(0)" ::: "memory");
    }
    __builtin_amdgcn_s_barrier();
  }

  // epilogue
#pragma unroll
  for (int i = 0; i < 8; ++i) {
#pragma unroll
    for (int j = 0; j < 4; ++j) {
      const int gn = tn0 + wc * 64 + j * 16 + mlo;
      float gg = 1.0f, bb = 0.0f;
      if (EPI == 1) {
        gg = (gn < 1024) ? g0[gn] : g1[gn - 1024];
        bb = (gn < 1024) ? b0[gn] : b1[gn - 1024];
      }
#pragma unroll
      for (int r = 0; r < 4; ++r) {
        const int gm = tm0 + wr * 128 + i * 16 + qd * 4 + r;
        float y = acc[i][j][r];
        if (EPI == 0) {
          y = y / (1.0f + __expf(-y));  // silu
        } else {
          y = (y * gg + bb) * scale;
        }
        Cout[(size_t)gm * ldC + gn] = (f16)y;
      }
    }
  }
}

// ---------------- QK^T (causal, masked, relu^2) -> P~ (f16) ----------------
// 64x128 tiles: active iff 2*kt <= qt -> 72 tiles/batch, 2304 blocks total.
// q,k pre-scaled by 2^11 each => acc = S * 2^22.  P~ = relu(acc*sparse_w)^2 (masked).
__global__ __launch_bounds__(256) void qk_kernel(
    const f16* __restrict__ QK,  // (32768 x 2048): cols [0,1024)=q~, [1024,2048)=k~
    const int* __restrict__ mask, const float* __restrict__ sparse_w,
    f16* __restrict__ P) {
  const int qt = blockIdx.x, kt = blockIdx.y, b = blockIdx.z;
  if (kt * 2 > qt) return;
  const f16* A = QK + (size_t)b * L * 2048;          // q~ rows of this batch
  const f16* B = QK + (size_t)b * L * 2048 + 1024;   // k~ rows
  const int* mb = mask + b * L;
  f16* Pb = P + (size_t)b * L * L;
  __shared__ f16 As[4][64][8];    // 4KB
  __shared__ f16 Bs[4][128][8];   // 8KB
  const int tm0 = qt * 64, tn0 = kt * 128;
  const int tid = threadIdx.x;
  const int w = tid >> 6, l = tid & 63;
  const int wr = w >> 1, wc = w & 1;   // wave covers 32 rows x 64 cols
  const int qd = l >> 4, mlo = l & 15;
  f32x4 acc[2][4] = {};
  for (int k0 = 0; k0 < L; k0 += 32) {
    // A: 64 rows x 32k = 4KB = one block-wide load; wave w stages k-chunk q=w
    load16_lds(A + (size_t)(tm0 + l) * 2048 + k0 + w * 8, &As[w][0][0]);
#pragma unroll
    for (int s = 0; s < 2; ++s)
      load16_lds(B + (size_t)(tn0 + s * 64 + l) * 2048 + k0 + w * 8, &Bs[w][s * 64][0]);
    __syncthreads();
    f16x8 af[2], bf[4];
#pragma unroll
    for (int i = 0; i < 2; ++i) af[i] = *(const f16x8*)&As[qd][wr * 32 + i * 16 + mlo][0];
#pragma unroll
    for (int j = 0; j < 4; ++j) bf[j] = *(const f16x8*)&Bs[qd][wc * 64 + j * 16 + mlo][0];
#pragma unroll
    for (int i = 0; i < 2; ++i)
#pragma unroll
      for (int j = 0; j < 4; ++j)
        acc[i][j] = __builtin_amdgcn_mfma_f32_16x16x32_f16(af[i], bf[j], acc[i][j], 0, 0, 0);
    __syncthreads();
  }
#pragma unroll
  for (int i = 0; i < 2; ++i) {
#pragma unroll
    for (int j = 0; j < 4; ++j) {
      const int gk = tn0 + wc * 64 + j * 16 + mlo;
      const int mk = mb[gk];
#pragma unroll
      for (int r = 0; r < 4; ++r) {
        const int gq = tm0 + wr * 32 + i * 16 + qd * 4 + r;
        float p = 0.0f;
        const bool blocked = (gk > gq) || ((gk != gq) && (mk == 0));
        if (!blocked) {
          p = acc[i][j][r] * sparse_w[(size_t)gq * L + gk];
          p = fmaxf(p, 0.0f);
          p = p * p;
        }
        Pb[(size_t)gq * L + gk] = (f16)p;
      }
    }
  }
}

// ---------------- PV: out = (P~ @ V) * 2^-64 (causal K-bound), f32 out ----------------
__global__ __launch_bounds__(256) void pv_kernel(
    const f16* __restrict__ P, const f16* __restrict__ Vt, float* __restrict__ Out) {
  const int qt = blockIdx.x, nt = blockIdx.y, b = blockIdx.z;
  const f16* A = P + (size_t)b * L * L;
  const f16* B = Vt + (size_t)b * L * DD;  // Vt is [d][ki] per batch
  float* outb = Out + (size_t)b * L * DD;
  const int kmax = (qt + 1) * 128;
  __shared__ f16 As[4][128][8];
  __shared__ f16 Bs[4][128][8];
  const int tm0 = qt * 128, tn0 = nt * 128;
  const int tid = threadIdx.x;
  const int w = tid >> 6, l = tid & 63;
  const int wr = w >> 1, wc = w & 1;
  const int qd = l >> 4, mlo = l & 15;
  f32x4 acc[4][4] = {};
  for (int k0 = 0; k0 < kmax; k0 += 32) {
#pragma unroll
    for (int s = 0; s < 2; ++s) {
      const int t = w * 2 + s;
      const int q = t >> 1, mh = t & 1;
      load16_lds(A + (size_t)(tm0 + mh * 64 + l) * L + k0 + q * 8, &As[q][mh * 64][0]);
      load16_lds(B + (size_t)(tn0 + mh * 64 + l) * L + k0 + q * 8, &Bs[q][mh * 64][0]);
    }
    __syncthreads();
    f16x8 af[4], bf[4];
#pragma unroll
    for (int i = 0; i < 4; ++i) af[i] = *(const f16x8*)&As[qd][wr * 64 + i * 16 + mlo][0];
#pragma unroll
    for (int j = 0; j < 4; ++j) bf[j] = *(const f16x8*)&Bs[qd][wc * 64 + j * 16 + mlo][0];
#pragma unroll
    for (int i = 0; i < 4; ++i)
#pragma unroll
      for (int j = 0; j < 4; ++j)
        acc[i][j] = __builtin_amdgcn_mfma_f32_16x16x32_f16(af[i], bf[j], acc[i][j], 0, 0, 0);
    __syncthreads();
  }
  const float fin = 5.421010862427522e-20f;  // 2^-64 = 2^-44 (qk scales) * 2^-20 (1/(L*D))
#pragma unroll
  for (int i = 0; i < 4; ++i) {
#pragma unroll
    for (int j = 0; j < 4; ++j) {
#pragma unroll
      for (int r = 0; r < 4; ++r) {
        const int gq = tm0 + wr * 64 + i * 16 + qd * 4 + r;
        const int gd = tn0 + wc * 64 + j * 16 + mlo;
        outb[(size_t)gq * DD + gd] = acc[i][j][r] * fin;
      }
    }
  }
}

// ---------------- launch ----------------
extern "C" void kernel_launch(void* const* d_in, const int* in_sizes, int n_in,
                              void* d_out, int out_size, void* d_ws, size_t ws_size,
                              hipStream_t stream) {
  const int* positives = (const int*)d_in[0];
  const int* mask = (const int*)d_in[1];
  const float* item_emb = (const float*)d_in[2];
  const float* pos_emb = (const float*)d_in[3];
  const float* Wz = (const float*)d_in[4];
  const float* Wv = (const float*)d_in[5];
  const float* Wq = (const float*)d_in[6];
  const float* Wk = (const float*)d_in[7];
  const float* gamma_q = (const float*)d_in[8];   // (2,L) -> head 0 = first L
  const float* beta_q = (const float*)d_in[9];
  const float* gamma_k = (const float*)d_in[10];
  const float* beta_k = (const float*)d_in[11];
  const float* sparse_w = (const float*)d_in[12];
  float* out = (float*)d_out;

  char* ws = (char*)d_ws;
  const size_t MB = 1024 * 1024;
  // layout (peak 264MB, known-good):
  //  [0,2)   Wzh      [2,4)  Wvh      [4,8)  Wqkh (stacked 2048x1024)
  //  [8,72)  bufZ: z, later vT
  //  [72,136) bufV: v, later P~
  //  [136,264) bufQK: x (first 64MB, dead after v-gemm), then q~|k~ (128MB)
  f16* Wzh = (f16*)(ws + 0 * MB);
  f16* Wvh = (f16*)(ws + 2 * MB);
  f16* Wqkh = (f16*)(ws + 4 * MB);
  f16* bufZ = (f16*)(ws + 8 * MB);
  f16* bufV = (f16*)(ws + 72 * MB);
  f16* bufQK = (f16*)(ws + 136 * MB);
  f16* bufX = bufQK;  // x occupies first 64MB of QK region until overwritten

  // opt-in to 128KB dynamic LDS (one-time; ignore errors, clear sticky state)
  static bool attr_set = false;
  if (!attr_set) {
    hipFuncSetAttribute(reinterpret_cast<const void*>(gemm256_kernel<0, 4>),
                        hipFuncAttributeMaxDynamicSharedMemorySize, 131072);
    hipFuncSetAttribute(reinterpret_cast<const void*>(gemm256_kernel<1, 8>),
                        hipFuncAttributeMaxDynamicSharedMemorySize, 131072);
    (void)hipGetLastError();
    attr_set = true;
  }

  cast_w_kernel<<<1024, 256, 0, stream>>>(Wz, Wzh);
  cast_w_kernel<<<1024, 256, 0, stream>>>(Wv, Wvh);
  cast_w_kernel<<<1024, 256, 0, stream>>>(Wq, Wqkh);             // rows [0,1024)
  cast_w_kernel<<<1024, 256, 0, stream>>>(Wk, Wqkh + 1024 * 1024);  // rows [1024,2048)
  gather_x_kernel<<<M_TOTAL, 256, 0, stream>>>(positives, item_emb, pos_emb, bufX);

  // z = silu(x Wz^T), v = silu(x Wv^T): 128 m-tiles x 4 n-tiles = 512 blocks
  gemm256_kernel<0, 4><<<512, 512, 131072, stream>>>(
      bufX, Wzh, bufZ, 1024, 1024, nullptr, nullptr, nullptr, nullptr, 1.0f);
  gemm256_kernel<0, 4><<<512, 512, 131072, stream>>>(
      bufX, Wvh, bufV, 1024, 1024, nullptr, nullptr, nullptr, nullptr, 1.0f);
  // [q~|k~] = (z [Wq;Wk]^T * gamma + beta) * 2^11 -> bufQK (overwrites dead x)
  gemm256_kernel<1, 8><<<1024, 512, 131072, stream>>>(
      bufZ, Wqkh, bufQK, 1024, 2048, gamma_q, beta_q, gamma_k, beta_k, 2048.0f);
  // vT (overwrites z in bufZ — safe: qk-proj already consumed z, stream-ordered)
  const dim3 gt(16, 16, BATCH);
  transpose_v_kernel<<<gt, 256, 0, stream>>>((const unsigned short*)bufV, (unsigned short*)bufZ);
  // P~ = relu(S~ * sparse_w)^2 masked (overwrites v in bufV)
  const dim3 gqk(16, 8, BATCH);
  qk_kernel<<<gqk, 256, 0, stream>>>(bufQK, mask, sparse_w, bufV);
  // out = (P~ @ V) * 2^-64
  const dim3 gpv(8, 8, BATCH);
  pv_kernel<<<gpv, 256, 0, stream>>>(bufV, bufZ, out);
}

// Round 2
// 1014.626 us; speedup vs baseline: 1.2519x; 1.1154x over previous
//
#include <hip/hip_runtime.h>

#define L 1024
#define DD 1024
#define BATCH 32
#define M_TOTAL (BATCH * L)  // 32768

typedef _Float16 f16;
typedef __attribute__((ext_vector_type(4))) _Float16 f16x4;
typedef __attribute__((ext_vector_type(8))) _Float16 f16x8;
typedef __attribute__((ext_vector_type(4))) float f32x4;

// async global->LDS, 16B per lane. LDS dest = wave-uniform base + lane*16.
__device__ __forceinline__ void load16_lds(const void* g, void* l) {
  __builtin_amdgcn_global_load_lds(
      (const __attribute__((address_space(1))) unsigned int*)g,
      (__attribute__((address_space(3))) unsigned int*)l,
      16, 0, 0);
}

// ---------------- small prep kernels ----------------

__global__ void gather_x_kernel(const int* __restrict__ positives,
                                const float* __restrict__ item_emb,
                                const float* __restrict__ pos_emb,
                                f16* __restrict__ x) {
  const int bl = blockIdx.x;
  const int lpos = bl & (L - 1);
  const int idx = positives[bl];
  const int d = threadIdx.x * 4;
  const float4 ie = *(const float4*)(item_emb + (size_t)idx * DD + d);
  const float4 pe = *(const float4*)(pos_emb + (size_t)lpos * DD + d);
  f16x4 h;
  h[0] = (f16)(ie.x + pe.x);
  h[1] = (f16)(ie.y + pe.y);
  h[2] = (f16)(ie.z + pe.z);
  h[3] = (f16)(ie.w + pe.w);
  *(f16x4*)(x + (size_t)bl * DD + d) = h;
}

__global__ void cast_w_kernel(const float* __restrict__ src, f16* __restrict__ dst) {
  const int i = (blockIdx.x * 256 + threadIdx.x) * 4;
  const float4 v = *(const float4*)(src + i);
  f16x4 h;
  h[0] = (f16)v.x; h[1] = (f16)v.y; h[2] = (f16)v.z; h[3] = (f16)v.w;
  *(f16x4*)(dst + i) = h;
}

// per-batch 1024x1024 f16 transpose via 64x64 LDS tiles
__global__ void transpose_v_kernel(const unsigned short* __restrict__ vin,
                                   unsigned short* __restrict__ vout) {
  const int b = blockIdx.z;
  const unsigned short* in = vin + (size_t)b * L * DD;
  unsigned short* out = vout + (size_t)b * L * DD;
  const int r0 = blockIdx.x * 64, c0 = blockIdx.y * 64;
  __shared__ unsigned short t[64][65];
  const int tid = threadIdx.x;
  for (int c = tid; c < 1024; c += 256) {
    const int r = c >> 4, cc = (c & 15) * 4;
    const ushort4 vv = *(const ushort4*)(in + (size_t)(r0 + r) * DD + c0 + cc);
    t[r][cc] = vv.x; t[r][cc + 1] = vv.y; t[r][cc + 2] = vv.z; t[r][cc + 3] = vv.w;
  }
  __syncthreads();
  for (int c = tid; c < 1024; c += 256) {
    const int r = c >> 4, cc = (c & 15) * 4;
    ushort4 vv;
    vv.x = t[cc][r]; vv.y = t[cc + 1][r]; vv.z = t[cc + 2][r]; vv.w = t[cc + 3][r];
    *(ushort4*)(out + (size_t)(c0 + r) * L + r0 + cc) = vv;
  }
}

// ---------------- shared 256x256 8-phase MFMA pipeline ----------------
// BK=64, 8 waves (2M x 4N), 512 threads, 128KB dynamic LDS double-buffer.
// Counted vmcnt(8) at tile boundaries (never 0 until the last tile); stages for
// tile t+2 issue in phases 2-3 of tile t (after buffer d's reads completed).
// LDS layout per buf/mat: [chunk c=k/8][row][8 f16] -> conflict-free ds_read_b128
// (measured SQ_LDS_BANK_CONFLICT == 0 on this layout).

#define LDSOFF(d, mt, c, r) (((((d) * 2 + (mt)) * 8 + (c)) * 256 + (r)) * 8)

__device__ __forceinline__ void pipeline256(
    const f16* __restrict__ Ag, const size_t ldA,
    const f16* __restrict__ Bg, const size_t ldB,
    f16* __restrict__ lds, f32x4 (&acc)[8][4],
    const int tid, const int nkt) {
  const int w = tid >> 6, l = tid & 63;
  const int wr = w >> 2, wc = w & 3;     // wave tile: rows wr*128+, cols wc*64+
  const int qd = l >> 4, mlo = l & 15;
  const int c1 = w >> 1, rbh = w & 1;    // staging task split

  auto stageA = [&](int dd, int h, int k0) {
    const int rb = h * 2 + rbh;
    load16_lds(Ag + (size_t)(rb * 64 + l) * ldA + k0 + c1 * 8,
               lds + LDSOFF(dd, 0, c1, rb * 64));
    load16_lds(Ag + (size_t)(rb * 64 + l) * ldA + k0 + (c1 + 4) * 8,
               lds + LDSOFF(dd, 0, c1 + 4, rb * 64));
  };
  auto stageB = [&](int dd, int h, int k0) {
    const int rb = h * 2 + rbh;
    load16_lds(Bg + (size_t)(rb * 64 + l) * ldB + k0 + c1 * 8,
               lds + LDSOFF(dd, 1, c1, rb * 64));
    load16_lds(Bg + (size_t)(rb * 64 + l) * ldB + k0 + (c1 + 4) * 8,
               lds + LDSOFF(dd, 1, c1 + 4, rb * 64));
  };

  // prologue: tile 0 fully (8 loads, oldest), then tile 1 fully (8 loads)
  stageA(0, 0, 0); stageA(0, 1, 0); stageB(0, 0, 0); stageB(0, 1, 0);
  asm volatile("" ::: "memory");  // keep t0 loads older than t1 loads
  stageA(1, 0, 64); stageA(1, 1, 64); stageB(1, 0, 64); stageB(1, 1, 64);
  asm volatile("s_waitcnt vmcnt(8)" ::: "memory");  // t0 landed; t1 (8) in flight
  __builtin_amdgcn_s_barrier();

#define LDA(mi, s) (*(const f16x8*)(lds + LDSOFF(d, 0, (s) * 4 + qd, wr * 128 + (mi) * 16 + mlo)))
#define LDB(ni, s) (*(const f16x8*)(lds + LDSOFF(d, 1, (s) * 4 + qd, wc * 64 + (ni) * 16 + mlo)))
#define MFMA16(a, b, c) __builtin_amdgcn_mfma_f32_16x16x32_f16(a, b, c, 0, 0, 0)

#pragma unroll 2
  for (int t = 0; t < nkt; ++t) {
    const int d = t & 1;
    const int k2 = (t + 2) * 64;
    const bool more = (t < nkt - 2);
    f16x8 a0[4][2], a1[4][2], bA[2][2], bB[2][2];
    // ---- phase 0: read A m0-3, B n0-1; MFMA Q(0,0)
#pragma unroll
    for (int m = 0; m < 4; ++m) { a0[m][0] = LDA(m, 0); a0[m][1] = LDA(m, 1); }
#pragma unroll
    for (int n = 0; n < 2; ++n) { bA[n][0] = LDB(n, 0); bA[n][1] = LDB(n, 1); }
    __builtin_amdgcn_s_barrier();
    __builtin_amdgcn_s_setprio(1);
#pragma unroll
    for (int m = 0; m < 4; ++m)
#pragma unroll
      for (int n = 0; n < 2; ++n) {
        acc[m][n] = MFMA16(a0[m][0], bA[n][0], acc[m][n]);
        acc[m][n] = MFMA16(a0[m][1], bA[n][1], acc[m][n]);
      }
    __builtin_amdgcn_s_setprio(0);
    __builtin_amdgcn_s_barrier();
    // ---- phase 1: read B n2-3; MFMA Q(0,1)
#pragma unroll
    for (int n = 0; n < 2; ++n) { bB[n][0] = LDB(n + 2, 0); bB[n][1] = LDB(n + 2, 1); }
    __builtin_amdgcn_s_barrier();
    __builtin_amdgcn_s_setprio(1);
#pragma unroll
    for (int m = 0; m < 4; ++m)
#pragma unroll
      for (int n = 0; n < 2; ++n) {
        acc[m][n + 2] = MFMA16(a0[m][0], bB[n][0], acc[m][n + 2]);
        acc[m][n + 2] = MFMA16(a0[m][1], bB[n][1], acc[m][n + 2]);
      }
    __builtin_amdgcn_s_setprio(0);
    __builtin_amdgcn_s_barrier();
    // ---- phase 2: read A m4-7; stage B(t+2) into buf d; MFMA Q(1,0)
#pragma unroll
    for (int m = 0; m < 4; ++m) { a1[m][0] = LDA(m + 4, 0); a1[m][1] = LDA(m + 4, 1); }
    if (more) { stageB(d, 0, k2); stageB(d, 1, k2); }
    __builtin_amdgcn_s_barrier();
    __builtin_amdgcn_s_setprio(1);
#pragma unroll
    for (int m = 0; m < 4; ++m)
#pragma unroll
      for (int n = 0; n < 2; ++n) {
        acc[m + 4][n] = MFMA16(a1[m][0], bA[n][0], acc[m + 4][n]);
        acc[m + 4][n] = MFMA16(a1[m][1], bA[n][1], acc[m + 4][n]);
      }
    __builtin_amdgcn_s_setprio(0);
    __builtin_amdgcn_s_barrier();
    // ---- phase 3: stage A(t+2); MFMA Q(1,1); boundary: counted vmcnt(8)
    //      leaves tile t+2's 8 loads in flight, guarantees tile t+1 landed.
    if (more) { stageA(d, 0, k2); stageA(d, 1, k2); }
    __builtin_amdgcn_s_barrier();
    __builtin_amdgcn_s_setprio(1);
#pragma unroll
    for (int m = 0; m < 4; ++m)
#pragma unroll
      for (int n = 0; n < 2; ++n) {
        acc[m + 4][n + 2] = MFMA16(a1[m][0], bB[n][0], acc[m + 4][n + 2]);
        acc[m + 4][n + 2] = MFMA16(a1[m][1], bB[n][1], acc[m + 4][n + 2]);
      }
    __builtin_amdgcn_s_setprio(0);
    if (more) {
      asm volatile("s_waitcnt vmcnt(8)" ::: "memory");
    } else if (t == nkt - 2) {
      asm volatile("s_waitcnt vmcnt(0)" ::: "memory");
    }
    __builtin_amdgcn_s_barrier();
  }
#undef LDA
#undef LDB
#undef MFMA16
}

// ---------------- dense GEMM: C = A(MxK,ldA) * B^T (NxK, ld 1024) ----------------
// EPI 0: silu. EPI 1: (acc*gamma+beta)*scale with gn>=1024 -> (g1,b1).
template <int EPI, int NTN>  // NTN = N/256 (power of 2)
__global__ __launch_bounds__(512, 2) void gemm256_kernel(
    const f16* __restrict__ A, const f16* __restrict__ B, f16* __restrict__ Cout,
    const size_t ldA, const size_t ldC,
    const float* __restrict__ g0, const float* __restrict__ b0,
    const float* __restrict__ g1, const float* __restrict__ b1, const float scale) {
  extern __shared__ f16 lds[];  // [2 buf][2 mat][8 chunk][256 row][8] = 128KB
  const int bid = blockIdx.x;
  const int cpx = gridDim.x >> 3;                    // blocks per XCD (grid % 8 == 0)
  const int logical = (bid & 7) * cpx + (bid >> 3);  // contiguous range per XCD
  const int mt = logical / NTN, nt = logical % NTN;
  const int tm0 = mt * 256, tn0 = nt * 256;
  const int tid = threadIdx.x;

  f32x4 acc[8][4] = {};
  pipeline256(A + (size_t)tm0 * ldA, ldA, B + (size_t)tn0 * 1024, 1024, lds, acc, tid, 16);

  const int w = tid >> 6, l = tid & 63;
  const int wr = w >> 2, wc = w & 3;
  const int qd = l >> 4, mlo = l & 15;
#pragma unroll
  for (int i = 0; i < 8; ++i) {
#pragma unroll
    for (int j = 0; j < 4; ++j) {
      const int gn = tn0 + wc * 64 + j * 16 + mlo;
      float gg = 1.0f, bb = 0.0f;
      if (EPI == 1) {
        gg = (gn < 1024) ? g0[gn] : g1[gn - 1024];
        bb = (gn < 1024) ? b0[gn] : b1[gn - 1024];
      }
#pragma unroll
      for (int r = 0; r < 4; ++r) {
        const int gm = tm0 + wr * 128 + i * 16 + qd * 4 + r;
        float y = acc[i][j][r];
        if (EPI == 0) {
          y = y / (1.0f + __expf(-y));  // silu
        } else {
          y = (y * gg + bb) * scale;
        }
        Cout[(size_t)gm * ldC + gn] = (f16)y;
      }
    }
  }
}

// ---------------- QK^T 256x256 causal (masked, relu^2) -> P~ (f16) ----------------
// Active tiles: nt <= mt (10/batch), 320 blocks. q,k pre-scaled by 2^11 each =>
// acc = S*2^22. P~ = relu(acc*sparse_w)^2 masked. Diagonal tiles write masked
// zeros over the full 256x256 (pv reads cols < 256*(mt+1), all covered).
__global__ __launch_bounds__(512, 2) void qk256_kernel(
    const f16* __restrict__ QK,  // (32768 x 2048): cols [0,1024)=q~, [1024,2048)=k~
    const int* __restrict__ mask, const float* __restrict__ sparse_w,
    f16* __restrict__ P) {
  extern __shared__ f16 lds[];
  const int bid = blockIdx.x;
  const int logical = (bid & 7) * 40 + (bid >> 3);  // 40 = 320/8 blocks per XCD
  const int b = logical / 10;
  const int t10 = logical - b * 10;
  int mt, nt;
  if (t10 == 0)      { mt = 0; nt = 0; }
  else if (t10 <= 2) { mt = 1; nt = t10 - 1; }
  else if (t10 <= 5) { mt = 2; nt = t10 - 3; }
  else               { mt = 3; nt = t10 - 6; }
  const int tm0 = mt * 256, tn0 = nt * 256;
  const f16* Ag = QK + (size_t)b * L * 2048 + (size_t)tm0 * 2048;         // q~ rows
  const f16* Bg = QK + (size_t)b * L * 2048 + 1024 + (size_t)tn0 * 2048;  // k~ rows
  const int tid = threadIdx.x;

  f32x4 acc[8][4] = {};
  pipeline256(Ag, 2048, Bg, 2048, lds, acc, tid, 16);

  const int w = tid >> 6, l = tid & 63;
  const int wr = w >> 2, wc = w & 3;
  const int qd = l >> 4, mlo = l & 15;
  const int* mb = mask + b * L;
  f16* Pb = P + (size_t)b * L * L;
#pragma unroll
  for (int i = 0; i < 8; ++i) {
#pragma unroll
    for (int j = 0; j < 4; ++j) {
      const int gk = tn0 + wc * 64 + j * 16 + mlo;
      const int mk = mb[gk];
#pragma unroll
      for (int r = 0; r < 4; ++r) {
        const int gq = tm0 + wr * 128 + i * 16 + qd * 4 + r;
        float p = 0.0f;
        const bool blocked = (gk > gq) || ((gk != gq) && (mk == 0));
        if (!blocked) {
          p = acc[i][j][r] * sparse_w[(size_t)gq * L + gk];
          p = fmaxf(p, 0.0f);
          p = p * p;
        }
        Pb[(size_t)gq * L + gk] = (f16)p;
      }
    }
  }
}

// ---------------- PV 256x256: out = (P~ @ V) * 2^-64, f32 out ----------------
// kmax = 256*(mt+1) (causal, rounded to tile); nkt = 4*(mt+1) in {4,8,12,16}.
__global__ __launch_bounds__(512, 2) void pv256_kernel(
    const f16* __restrict__ P, const f16* __restrict__ Vt, float* __restrict__ Out) {
  extern __shared__ f16 lds[];
  const int bid = blockIdx.x;
  const int logical = (bid & 7) * 64 + (bid >> 3);  // 64 = 512/8 blocks per XCD
  const int b = logical >> 4;
  const int tile = logical & 15;
  const int mt = tile >> 2, nt = tile & 3;
  const int tm0 = mt * 256, tn0 = nt * 256;
  const f16* Ag = P + (size_t)b * L * L + (size_t)tm0 * L;    // P~ rows
  const f16* Bg = Vt + (size_t)b * L * DD + (size_t)tn0 * L;  // Vt rows (d-major)
  const int tid = threadIdx.x;

  f32x4 acc[8][4] = {};
  pipeline256(Ag, L, Bg, L, lds, acc, tid, (mt + 1) * 4);

  const int w = tid >> 6, l = tid & 63;
  const int wr = w >> 2, wc = w & 3;
  const int qd = l >> 4, mlo = l & 15;
  float* outb = Out + (size_t)b * L * DD;
  const float fin = 5.421010862427522e-20f;  // 2^-64 = 2^-44 (qk scales) * 2^-20 (1/(L*D))
#pragma unroll
  for (int i = 0; i < 8; ++i) {
#pragma unroll
    for (int j = 0; j < 4; ++j) {
#pragma unroll
      for (int r = 0; r < 4; ++r) {
        const int gq = tm0 + wr * 128 + i * 16 + qd * 4 + r;
        const int gd = tn0 + wc * 64 + j * 16 + mlo;
        outb[(size_t)gq * DD + gd] = acc[i][j][r] * fin;
      }
    }
  }
}

// ---------------- launch ----------------
extern "C" void kernel_launch(void* const* d_in, const int* in_sizes, int n_in,
                              void* d_out, int out_size, void* d_ws, size_t ws_size,
                              hipStream_t stream) {
  const int* positives = (const int*)d_in[0];
  const int* mask = (const int*)d_in[1];
  const float* item_emb = (const float*)d_in[2];
  const float* pos_emb = (const float*)d_in[3];
  const float* Wz = (const float*)d_in[4];
  const float* Wv = (const float*)d_in[5];
  const float* Wq = (const float*)d_in[6];
  const float* Wk = (const float*)d_in[7];
  const float* gamma_q = (const float*)d_in[8];   // (2,L) -> head 0 = first L
  const float* beta_q = (const float*)d_in[9];
  const float* gamma_k = (const float*)d_in[10];
  const float* beta_k = (const float*)d_in[11];
  const float* sparse_w = (const float*)d_in[12];
  float* out = (float*)d_out;

  char* ws = (char*)d_ws;
  const size_t MB = 1024 * 1024;
  // layout (peak 264MB, known-good):
  //  [0,2)   Wzh      [2,4)  Wvh      [4,8)  Wqkh (stacked 2048x1024)
  //  [8,72)  bufZ: z, later vT
  //  [72,136) bufV: v, later P~
  //  [136,264) bufQK: x (first 64MB, dead after v-gemm), then q~|k~ (128MB)
  f16* Wzh = (f16*)(ws + 0 * MB);
  f16* Wvh = (f16*)(ws + 2 * MB);
  f16* Wqkh = (f16*)(ws + 4 * MB);
  f16* bufZ = (f16*)(ws + 8 * MB);
  f16* bufV = (f16*)(ws + 72 * MB);
  f16* bufQK = (f16*)(ws + 136 * MB);
  f16* bufX = bufQK;  // x occupies first 64MB of QK region until overwritten

  // opt-in to 128KB dynamic LDS (one-time; clear sticky state)
  static bool attr_set = false;
  if (!attr_set) {
    hipFuncSetAttribute(reinterpret_cast<const void*>(gemm256_kernel<0, 4>),
                        hipFuncAttributeMaxDynamicSharedMemorySize, 131072);
    hipFuncSetAttribute(reinterpret_cast<const void*>(gemm256_kernel<1, 8>),
                        hipFuncAttributeMaxDynamicSharedMemorySize, 131072);
    hipFuncSetAttribute(reinterpret_cast<const void*>(qk256_kernel),
                        hipFuncAttributeMaxDynamicSharedMemorySize, 131072);
    hipFuncSetAttribute(reinterpret_cast<const void*>(pv256_kernel),
                        hipFuncAttributeMaxDynamicSharedMemorySize, 131072);
    (void)hipGetLastError();
    attr_set = true;
  }

  cast_w_kernel<<<1024, 256, 0, stream>>>(Wz, Wzh);
  cast_w_kernel<<<1024, 256, 0, stream>>>(Wv, Wvh);
  cast_w_kernel<<<1024, 256, 0, stream>>>(Wq, Wqkh);             // rows [0,1024)
  cast_w_kernel<<<1024, 256, 0, stream>>>(Wk, Wqkh + 1024 * 1024);  // rows [1024,2048)
  gather_x_kernel<<<M_TOTAL, 256, 0, stream>>>(positives, item_emb, pos_emb, bufX);

  // z = silu(x Wz^T), v = silu(x Wv^T): 128 m-tiles x 4 n-tiles = 512 blocks
  gemm256_kernel<0, 4><<<512, 512, 131072, stream>>>(
      bufX, Wzh, bufZ, 1024, 1024, nullptr, nullptr, nullptr, nullptr, 1.0f);
  gemm256_kernel<0, 4><<<512, 512, 131072, stream>>>(
      bufX, Wvh, bufV, 1024, 1024, nullptr, nullptr, nullptr, nullptr, 1.0f);
  // [q~|k~] = (z [Wq;Wk]^T * gamma + beta) * 2^11 -> bufQK (overwrites dead x)
  gemm256_kernel<1, 8><<<1024, 512, 131072, stream>>>(
      bufZ, Wqkh, bufQK, 1024, 2048, gamma_q, beta_q, gamma_k, beta_k, 2048.0f);
  // vT (overwrites z in bufZ — safe: qk-proj already consumed z, stream-ordered)
  const dim3 gt(16, 16, BATCH);
  transpose_v_kernel<<<gt, 256, 0, stream>>>((const unsigned short*)bufV, (unsigned short*)bufZ);
  // P~ = relu(S~ * sparse_w)^2 masked, 256^2 causal tiles (overwrites v in bufV)
  qk256_kernel<<<320, 512, 131072, stream>>>(bufQK, mask, sparse_w, bufV);
  // out = (P~ @ V) * 2^-64, 256^2 tiles
  pv256_kernel<<<512, 512, 131072, stream>>>(bufV, bufZ, out);
}